// Round 8
// baseline (507.568 us; speedup 1.0000x reference)
//
#include <hip/hip_runtime.h>
#include <hip/hip_bf16.h>
#include <hip/hip_fp16.h>
#include <cstdint>
#include <cstddef>

typedef _Float16 h8 __attribute__((ext_vector_type(8)));
typedef float f4 __attribute__((ext_vector_type(4)));

#define CNT_PAD 16   // one counter per 64B line

// ---------------- CSR build ----------------

// rank[i] = arrival order of edge i at its dst; cnt_pad[d*16] = in-degree (excl. self-loop)
__global__ __launch_bounds__(256) void k_count_rank(const int* __restrict__ dst, int* __restrict__ cnt_pad,
                                                    int* __restrict__ rank, int E) {
    int i = blockIdx.x * 256 + threadIdx.x;
    if (i < E) rank[i] = atomicAdd(&cnt_pad[(size_t)dst[i] * CNT_PAD], 1);
}

__global__ __launch_bounds__(256) void k_scan_a(const int* __restrict__ cnt_pad, int* __restrict__ offs,
                                                int* __restrict__ partials, float* __restrict__ dinv, int N) {
    __shared__ int sh[256];
    int t = threadIdx.x;
    int i = blockIdx.x * 256 + t;
    int v = (i < N) ? (cnt_pad[(size_t)i * CNT_PAD] + 1) : 0;
    sh[t] = v;
    __syncthreads();
    for (int d = 1; d < 256; d <<= 1) {
        int add = (t >= d) ? sh[t - d] : 0;
        __syncthreads();
        sh[t] += add;
        __syncthreads();
    }
    if (i < N) {
        offs[i] = sh[t] - v;
        dinv[i] = rsqrtf((float)v);
    }
    if (t == 255) partials[blockIdx.x] = sh[255];
}

__global__ __launch_bounds__(512) void k_scan_b(int* __restrict__ partials, int nb) {
    __shared__ int sh[512];
    int t = threadIdx.x;
    int v = (t < nb) ? partials[t] : 0;
    sh[t] = v;
    __syncthreads();
    for (int d = 1; d < 512; d <<= 1) {
        int add = (t >= d) ? sh[t - d] : 0;
        __syncthreads();
        sh[t] += add;
        __syncthreads();
    }
    if (t < nb) partials[t] = sh[t];
}

__global__ __launch_bounds__(256) void k_scan_c(int* __restrict__ offs, const int* __restrict__ partials,
                                                int N, int nb) {
    int i = blockIdx.x * 256 + threadIdx.x;
    if (i < N) {
        int b = i >> 8;
        if (b > 0) offs[i] += partials[b - 1];
    } else if (i == N) {
        offs[N] = partials[nb - 1];
    }
}

// no atomic: pos = offs[dst] + rank; 1 edge per thread; NT scatter (bypass L2 bouncing)
__global__ __launch_bounds__(256) void k_fill2(const int* __restrict__ src, const int* __restrict__ dst,
                                               const int* __restrict__ rank, const int* __restrict__ offs,
                                               const float* __restrict__ dinv,
                                               long long* __restrict__ cpack, int E) {
    int i = blockIdx.x * 256 + threadIdx.x;
    if (i < E) {
        int s = src[i], d = dst[i];
        int pos = offs[d] + rank[i];
        unsigned int nrm = (unsigned int)__float_as_int(dinv[s] * dinv[d]);
        long long v = ((long long)nrm << 32) | (unsigned int)s;
        __builtin_nontemporal_store(v, &cpack[pos]);
    }
}

// self-loop sits at the end of each node's segment: offs[i+1]-1
__global__ __launch_bounds__(256) void k_fill_loops(const int* __restrict__ offs,
                                                    const float* __restrict__ dinv,
                                                    long long* __restrict__ cpack, int N) {
    int i = blockIdx.x * 256 + threadIdx.x;
    if (i < N) {
        float di = dinv[i];
        unsigned int nrm = (unsigned int)__float_as_int(di * di);
        long long v = ((long long)nrm << 32) | (unsigned int)i;
        __builtin_nontemporal_store(v, &cpack[offs[i + 1] - 1]);
    }
}

// ---------------- W -> W^T fp16 (once): WT[layer][c][k] = W_layer[k][c] ----------------

__global__ __launch_bounds__(256) void k_prep_w(const float* __restrict__ w0, const float* __restrict__ w1,
                                                const float* __restrict__ w2, _Float16* __restrict__ WT) {
    int idx = blockIdx.x * 256 + threadIdx.x;
    if (idx >= 3 * 16384) return;
    int l = idx >> 14, rem = idx & 16383, c = rem >> 7, k = rem & 127;
    const float* W = (l == 0) ? w0 : (l == 1) ? w1 : w2;
    WT[idx] = (_Float16)W[k * 128 + c];
}

// ---------------- node features: x = [emb[label], MLP(bbox)] -> fp16 ----------------

__global__ __launch_bounds__(256) void k_feat(const int* __restrict__ label, const float* __restrict__ bbox,
                                              const float* __restrict__ emb,
                                              const float* __restrict__ w1, const float* __restrict__ b1,
                                              const float* __restrict__ w2, const float* __restrict__ b2,
                                              __half* __restrict__ X, int N) {
    __shared__ float w1s[4 * 64];
    __shared__ float b1s[64], b2s[64];
    __shared__ float w2s[64 * 64];
    __shared__ float h1s[4][64];
    int t = threadIdx.x;
    if (t < 256) w1s[t] = w1[t];
    if (t < 64) { b1s[t] = b1[t]; b2s[t] = b2[t]; }
    for (int i = t; i < 64 * 64; i += 256) w2s[i] = w2[i];
    __syncthreads();

    int wave = t >> 6, lane = t & 63;
    int node = blockIdx.x * 4 + wave;
    bool ok = node < N;

    float h1 = 0.f;
    if (ok) {
        float bb0 = bbox[node * 4 + 0];
        float bb1 = bbox[node * 4 + 1];
        float bb2 = bbox[node * 4 + 2];
        float bb3 = bbox[node * 4 + 3];
        h1 = bb0 * w1s[0 * 64 + lane] + bb1 * w1s[1 * 64 + lane]
           + bb2 * w1s[2 * 64 + lane] + bb3 * w1s[3 * 64 + lane] + b1s[lane];
        h1 = fmaxf(h1, 0.f);
    }
    h1s[wave][lane] = h1;
    __syncthreads();

    if (ok) {
        float acc = b2s[lane];
        #pragma unroll 8
        for (int k = 0; k < 64; ++k) acc += h1s[wave][k] * w2s[k * 64 + lane];
        int lb = label[node];
        X[(size_t)node * 128 + lane] = __float2half(emb[(size_t)lb * 64 + lane]);
        X[(size_t)node * 128 + 64 + lane] = __float2half(acc);
    }
}

// ---------------- MFMA GEMM: H[N][128] = X[N][128] @ W  (fp16 in/out, fp32 acc) ----------------

__global__ __launch_bounds__(256) void k_gemm_mfma(const _Float16* __restrict__ X,
                                                   const _Float16* __restrict__ WT,
                                                   _Float16* __restrict__ H, int N) {
    int t = threadIdx.x;
    int wv = t >> 6, lane = t & 63;
    int r = lane & 15, q = lane >> 4;
    int n0 = blockIdx.x * 64 + wv * 16;

    int arow = n0 + r; if (arow > N - 1) arow = N - 1;
    h8 a[4];
    #pragma unroll
    for (int s = 0; s < 4; ++s)
        a[s] = *(const h8*)&X[(size_t)arow * 128 + s * 32 + q * 8];

    #pragma unroll
    for (int ct = 0; ct < 8; ++ct) {
        h8 b[4];
        #pragma unroll
        for (int s = 0; s < 4; ++s)
            b[s] = *(const h8*)&WT[(size_t)(ct * 16 + r) * 128 + s * 32 + q * 8];
        f4 acc = {0.f, 0.f, 0.f, 0.f};
        #pragma unroll
        for (int s = 0; s < 4; ++s)
            acc = __builtin_amdgcn_mfma_f32_16x16x32_f16(a[s], b[s], acc, 0, 0, 0);
        #pragma unroll
        for (int i = 0; i < 4; ++i) {
            int row = n0 + q * 4 + i;
            if (row < N) H[(size_t)row * 128 + ct * 16 + r] = (_Float16)acc[i];
        }
    }
}

// ---------------- aggregation: Y[n] = relu?( sum_e norm_e * H[src_e] + b ) ----------------
// 1 wave per node; 4 groups x 16 lanes. Group g gathers edges {e+8g..e+8g+7} as
// dwordx4 (16 lanes x 16 B = full 256 B row per edge), 8 loads in flight;
// (s,w) broadcast via shfl; cross-group shfl_xor reduce once per node.

template <int OUT_HALF>
__global__ __launch_bounds__(256) void k_agg(const uint4* __restrict__ H4, const int* __restrict__ offs,
                                             const int2* __restrict__ cpack,
                                             const float* __restrict__ bias, void* __restrict__ Yv,
                                             int N, int do_relu) {
    int node = blockIdx.x * 4 + (threadIdx.x >> 6);
    if (node >= N) return;
    int lane = threadIdx.x & 63;
    int grp = lane >> 4, li = lane & 15;
    int i0 = offs[node], i1 = offs[node + 1];

    float acc[8];
    #pragma unroll
    for (int k = 0; k < 8; ++k) acc[k] = 0.f;

    for (int base = i0; base < i1; base += 64) {
        int navail = i1 - base; if (navail > 64) navail = 64;
        int lidx = lane < navail ? lane : (navail - 1);
        int2 ep = cpack[base + lidx];
        for (int e = 0; e < navail; e += 32) {
            int s[8]; float w[8];
            #pragma unroll
            for (int j = 0; j < 8; ++j) {
                int idx = e + 8 * grp + j;
                int cl = idx < navail ? idx : (navail - 1);
                s[j] = __shfl(ep.x, cl);
                float wj = __int_as_float(__shfl(ep.y, cl));
                w[j] = idx < navail ? wj : 0.f;
            }
            uint4 h[8];
            #pragma unroll
            for (int j = 0; j < 8; ++j) h[j] = H4[(size_t)s[j] * 16 + li];
            #pragma unroll
            for (int j = 0; j < 8; ++j) {
                float2 f;
                f = __half22float2(*(const __half2*)&h[j].x); acc[0] += f.x * w[j]; acc[1] += f.y * w[j];
                f = __half22float2(*(const __half2*)&h[j].y); acc[2] += f.x * w[j]; acc[3] += f.y * w[j];
                f = __half22float2(*(const __half2*)&h[j].z); acc[4] += f.x * w[j]; acc[5] += f.y * w[j];
                f = __half22float2(*(const __half2*)&h[j].w); acc[6] += f.x * w[j]; acc[7] += f.y * w[j];
            }
        }
    }

    // lanes l, l^16, l^32, l^48 hold partials of the same 8 columns
    #pragma unroll
    for (int k = 0; k < 8; ++k) {
        float v = acc[k];
        v += __shfl_xor(v, 16);
        v += __shfl_xor(v, 32);
        acc[k] = v;
    }

    if (grp == 0) {
        float4 b0 = *(const float4*)&bias[li * 8];
        float4 b1 = *(const float4*)&bias[li * 8 + 4];
        acc[0] += b0.x; acc[1] += b0.y; acc[2] += b0.z; acc[3] += b0.w;
        acc[4] += b1.x; acc[5] += b1.y; acc[6] += b1.z; acc[7] += b1.w;
        if (do_relu) {
            #pragma unroll
            for (int k = 0; k < 8; ++k) acc[k] = fmaxf(acc[k], 0.f);
        }
        if (OUT_HALF) {
            __half2 p0 = __float22half2_rn(make_float2(acc[0], acc[1]));
            __half2 p1 = __float22half2_rn(make_float2(acc[2], acc[3]));
            __half2 p2 = __float22half2_rn(make_float2(acc[4], acc[5]));
            __half2 p3 = __float22half2_rn(make_float2(acc[6], acc[7]));
            uint4 pk;
            pk.x = *(unsigned int*)&p0; pk.y = *(unsigned int*)&p1;
            pk.z = *(unsigned int*)&p2; pk.w = *(unsigned int*)&p3;
            ((uint4*)Yv)[(size_t)node * 16 + li] = pk;
        } else {
            float* Yf = (float*)Yv;
            *(float4*)&Yf[(size_t)node * 128 + li * 8]     = make_float4(acc[0], acc[1], acc[2], acc[3]);
            *(float4*)&Yf[(size_t)node * 128 + li * 8 + 4] = make_float4(acc[4], acc[5], acc[6], acc[7]);
        }
    }
}

// ---------------- launch ----------------

extern "C" void kernel_launch(void* const* d_in, const int* in_sizes, int n_in,
                              void* d_out, int out_size, void* d_ws, size_t ws_size,
                              hipStream_t stream) {
    const int*   label = (const int*)d_in[0];
    const float* bbox  = (const float*)d_in[1];
    const int*   eidx  = (const int*)d_in[2];
    const float* emb   = (const float*)d_in[3];
    const float* w1    = (const float*)d_in[4];
    const float* b1    = (const float*)d_in[5];
    const float* w2    = (const float*)d_in[6];
    const float* b2    = (const float*)d_in[7];
    const float* wg0   = (const float*)d_in[8];
    const float* bg0   = (const float*)d_in[9];
    const float* wg1   = (const float*)d_in[10];
    const float* bg1   = (const float*)d_in[11];
    const float* wg2   = (const float*)d_in[12];
    const float* bg2   = (const float*)d_in[13];

    int N = in_sizes[0];
    int E = in_sizes[2] / 2;
    const int* esrc = eidx;
    const int* edst = eidx + E;

    char* ws = (char*)d_ws;
    int*       offs     = (int*)      (ws + 0x80000);    // N+1 ints
    int*       partials = (int*)      (ws + 0x100000);   // <=512 ints
    float*     dinv     = (float*)    (ws + 0x180000);   // N floats
    _Float16*  WT       = (_Float16*) (ws + 0x1C0000);   // 3*128*128 halves (96 KB)
    long long* cpack    = (long long*)(ws + 0x200000);   // (E+N) int2 (~13.6 MB)
    __half*    F0       = (__half*)   (ws + 0x1000000);  // N*128 halves (25.6 MB)
    int*       cnt_pad  = (int*)      (ws + 0x1000000);  // N*16 ints (6.4 MB) — aliases F0[0:6.4M] (dead before k_feat)
    int*       rank     = (int*)      (ws + 0x1800000);  // E ints (6.4 MB) — aliases F0[8M:14.4M] (dead before k_feat)
    __half*    G        = (__half*)   (ws + 0x2900000);  // N*128 halves (25.6 MB)
    __half*    F1       = (__half*)   d_out;             // fp16 scratch (layer-1 window only)
    float*     Of       = (float*)    d_out;             // final fp32 output

    int nb = (N + 255) / 256;
    int eb = (E + 255) / 256;

    hipMemsetAsync(cnt_pad, 0, (size_t)N * CNT_PAD * 4, stream);
    k_count_rank<<<eb, 256, 0, stream>>>(edst, cnt_pad, rank, E);
    k_scan_a<<<nb, 256, 0, stream>>>(cnt_pad, offs, partials, dinv, N);
    k_scan_b<<<1, 512, 0, stream>>>(partials, nb);
    k_scan_c<<<(N + 1 + 255) / 256, 256, 0, stream>>>(offs, partials, N, nb);
    k_fill2<<<eb, 256, 0, stream>>>(esrc, edst, rank, offs, dinv, cpack, E);
    k_fill_loops<<<nb, 256, 0, stream>>>(offs, dinv, cpack, N);

    k_prep_w<<<192, 256, 0, stream>>>(wg0, wg1, wg2, WT);
    k_feat<<<(N + 3) / 4, 256, 0, stream>>>(label, bbox, emb, w1, b1, w2, b2, F0, N);

    int gemm_grid = (N + 63) / 64;
    int agg_grid  = (N + 3) / 4;

    // layer 0: G = F0 @ W0 ; F1 = relu(A_hat G + b0)
    k_gemm_mfma<<<gemm_grid, 256, 0, stream>>>((const _Float16*)F0, WT + 0 * 16384, (_Float16*)G, N);
    k_agg<1><<<agg_grid, 256, 0, stream>>>((const uint4*)G, offs, (const int2*)cpack, bg0, F1, N, 1);
    // layer 1: G = F1 @ W1 ; F0 = relu(A_hat G + b1)
    k_gemm_mfma<<<gemm_grid, 256, 0, stream>>>((const _Float16*)F1, WT + 1 * 16384, (_Float16*)G, N);
    k_agg<1><<<agg_grid, 256, 0, stream>>>((const uint4*)G, offs, (const int2*)cpack, bg1, F0, N, 1);
    // layer 2: G = F0 @ W2 ; d_out = A_hat G + b2   (fp32)
    k_gemm_mfma<<<gemm_grid, 256, 0, stream>>>((const _Float16*)F0, WT + 2 * 16384, (_Float16*)G, N);
    k_agg<0><<<agg_grid, 256, 0, stream>>>((const uint4*)G, offs, (const int2*)cpack, bg2, Of, N, 0);
}

// Round 9
// 476.957 us; speedup vs baseline: 1.0642x; 1.0642x over previous
//
#include <hip/hip_runtime.h>
#include <hip/hip_bf16.h>
#include <hip/hip_fp16.h>
#include <cstdint>
#include <cstddef>

typedef _Float16 h8 __attribute__((ext_vector_type(8)));
typedef float f4 __attribute__((ext_vector_type(4)));

#define CNT_PAD 16   // one counter per 64B line

// ---------------- CSR build ----------------

// rank[i] = arrival order of edge i at its dst; cnt_pad[d*16] = in-degree (excl. self-loop)
__global__ __launch_bounds__(256) void k_count_rank(const int* __restrict__ dst, int* __restrict__ cnt_pad,
                                                    int* __restrict__ rank, int E) {
    int i = blockIdx.x * 256 + threadIdx.x;
    if (i < E) rank[i] = atomicAdd(&cnt_pad[(size_t)dst[i] * CNT_PAD], 1);
}

__global__ __launch_bounds__(256) void k_scan_a(const int* __restrict__ cnt_pad, int* __restrict__ offs,
                                                int* __restrict__ partials, float* __restrict__ dinv, int N) {
    __shared__ int sh[256];
    int t = threadIdx.x;
    int i = blockIdx.x * 256 + t;
    int v = (i < N) ? (cnt_pad[(size_t)i * CNT_PAD] + 1) : 0;
    sh[t] = v;
    __syncthreads();
    for (int d = 1; d < 256; d <<= 1) {
        int add = (t >= d) ? sh[t - d] : 0;
        __syncthreads();
        sh[t] += add;
        __syncthreads();
    }
    if (i < N) {
        offs[i] = sh[t] - v;
        dinv[i] = rsqrtf((float)v);
    }
    if (t == 255) partials[blockIdx.x] = sh[255];
}

__global__ __launch_bounds__(512) void k_scan_b(int* __restrict__ partials, int nb) {
    __shared__ int sh[512];
    int t = threadIdx.x;
    int v = (t < nb) ? partials[t] : 0;
    sh[t] = v;
    __syncthreads();
    for (int d = 1; d < 512; d <<= 1) {
        int add = (t >= d) ? sh[t - d] : 0;
        __syncthreads();
        sh[t] += add;
        __syncthreads();
    }
    if (t < nb) partials[t] = sh[t];
}

__global__ __launch_bounds__(256) void k_scan_c(int* __restrict__ offs, const int* __restrict__ partials,
                                                int N, int nb) {
    int i = blockIdx.x * 256 + threadIdx.x;
    if (i < N) {
        int b = i >> 8;
        if (b > 0) offs[i] += partials[b - 1];
    } else if (i == N) {
        offs[N] = partials[nb - 1];
    }
}

// no atomic: pos = offs[dst] + rank; 1 edge per thread; NT scatter (bypass L2 bouncing)
__global__ __launch_bounds__(256) void k_fill2(const int* __restrict__ src, const int* __restrict__ dst,
                                               const int* __restrict__ rank, const int* __restrict__ offs,
                                               const float* __restrict__ dinv,
                                               long long* __restrict__ cpack, int E) {
    int i = blockIdx.x * 256 + threadIdx.x;
    if (i < E) {
        int s = src[i], d = dst[i];
        int pos = offs[d] + rank[i];
        unsigned int nrm = (unsigned int)__float_as_int(dinv[s] * dinv[d]);
        long long v = ((long long)nrm << 32) | (unsigned int)s;
        __builtin_nontemporal_store(v, &cpack[pos]);
    }
}

// self-loop sits at the end of each node's segment: offs[i+1]-1
__global__ __launch_bounds__(256) void k_fill_loops(const int* __restrict__ offs,
                                                    const float* __restrict__ dinv,
                                                    long long* __restrict__ cpack, int N) {
    int i = blockIdx.x * 256 + threadIdx.x;
    if (i < N) {
        float di = dinv[i];
        unsigned int nrm = (unsigned int)__float_as_int(di * di);
        long long v = ((long long)nrm << 32) | (unsigned int)i;
        __builtin_nontemporal_store(v, &cpack[offs[i + 1] - 1]);
    }
}

// ---------------- W -> W^T fp16 (once): WT[layer][c][k] = W_layer[k][c] ----------------

__global__ __launch_bounds__(256) void k_prep_w(const float* __restrict__ w0, const float* __restrict__ w1,
                                                const float* __restrict__ w2, _Float16* __restrict__ WT) {
    int idx = blockIdx.x * 256 + threadIdx.x;
    if (idx >= 3 * 16384) return;
    int l = idx >> 14, rem = idx & 16383, c = rem >> 7, k = rem & 127;
    const float* W = (l == 0) ? w0 : (l == 1) ? w1 : w2;
    WT[idx] = (_Float16)W[k * 128 + c];
}

// ---------------- node features: x = [emb[label], MLP(bbox)] -> fp16 ----------------

__global__ __launch_bounds__(256) void k_feat(const int* __restrict__ label, const float* __restrict__ bbox,
                                              const float* __restrict__ emb,
                                              const float* __restrict__ w1, const float* __restrict__ b1,
                                              const float* __restrict__ w2, const float* __restrict__ b2,
                                              __half* __restrict__ X, int N) {
    __shared__ float w1s[4 * 64];
    __shared__ float b1s[64], b2s[64];
    __shared__ float w2s[64 * 64];
    __shared__ float h1s[4][64];
    int t = threadIdx.x;
    if (t < 256) w1s[t] = w1[t];
    if (t < 64) { b1s[t] = b1[t]; b2s[t] = b2[t]; }
    for (int i = t; i < 64 * 64; i += 256) w2s[i] = w2[i];
    __syncthreads();

    int wave = t >> 6, lane = t & 63;
    int node = blockIdx.x * 4 + wave;
    bool ok = node < N;

    float h1 = 0.f;
    if (ok) {
        float bb0 = bbox[node * 4 + 0];
        float bb1 = bbox[node * 4 + 1];
        float bb2 = bbox[node * 4 + 2];
        float bb3 = bbox[node * 4 + 3];
        h1 = bb0 * w1s[0 * 64 + lane] + bb1 * w1s[1 * 64 + lane]
           + bb2 * w1s[2 * 64 + lane] + bb3 * w1s[3 * 64 + lane] + b1s[lane];
        h1 = fmaxf(h1, 0.f);
    }
    h1s[wave][lane] = h1;
    __syncthreads();

    if (ok) {
        float acc = b2s[lane];
        #pragma unroll 8
        for (int k = 0; k < 64; ++k) acc += h1s[wave][k] * w2s[k * 64 + lane];
        int lb = label[node];
        X[(size_t)node * 128 + lane] = __float2half(emb[(size_t)lb * 64 + lane]);
        X[(size_t)node * 128 + 64 + lane] = __float2half(acc);
    }
}

// ---------------- MFMA GEMM: H[N][128] = X[N][128] @ W  (fp16 in/out, fp32 acc) ----------------

__global__ __launch_bounds__(256) void k_gemm_mfma(const _Float16* __restrict__ X,
                                                   const _Float16* __restrict__ WT,
                                                   _Float16* __restrict__ H, int N) {
    int t = threadIdx.x;
    int wv = t >> 6, lane = t & 63;
    int r = lane & 15, q = lane >> 4;
    int n0 = blockIdx.x * 64 + wv * 16;

    int arow = n0 + r; if (arow > N - 1) arow = N - 1;
    h8 a[4];
    #pragma unroll
    for (int s = 0; s < 4; ++s)
        a[s] = *(const h8*)&X[(size_t)arow * 128 + s * 32 + q * 8];

    #pragma unroll
    for (int ct = 0; ct < 8; ++ct) {
        h8 b[4];
        #pragma unroll
        for (int s = 0; s < 4; ++s)
            b[s] = *(const h8*)&WT[(size_t)(ct * 16 + r) * 128 + s * 32 + q * 8];
        f4 acc = {0.f, 0.f, 0.f, 0.f};
        #pragma unroll
        for (int s = 0; s < 4; ++s)
            acc = __builtin_amdgcn_mfma_f32_16x16x32_f16(a[s], b[s], acc, 0, 0, 0);
        #pragma unroll
        for (int i = 0; i < 4; ++i) {
            int row = n0 + q * 4 + i;
            if (row < N) H[(size_t)row * 128 + ct * 16 + r] = (_Float16)acc[i];
        }
    }
}

// ---------------- aggregation: Y[n] = relu?( sum_e norm_e * H[src_e] + b ) ----------------
// One independent 16-lane group per node (16 nodes / 256-thr block). Group loads
// 16 edge records coalesced per window, processes 4 edges/step (4 dwordx4 rows
// in flight); lane li owns cols {8li..8li+7}. Requests/node ~= deg+3 (was ~2x).

template <int OUT_HALF>
__global__ __launch_bounds__(256) void k_agg(const uint4* __restrict__ H4, const int* __restrict__ offs,
                                             const int2* __restrict__ cpack,
                                             const float* __restrict__ bias, void* __restrict__ Yv,
                                             int N, int do_relu) {
    int node = blockIdx.x * 16 + (threadIdx.x >> 4);
    if (node >= N) return;
    int li = threadIdx.x & 15;
    int i0 = offs[node], i1 = offs[node + 1];

    float acc[8];
    #pragma unroll
    for (int k = 0; k < 8; ++k) acc[k] = 0.f;

    for (int base = i0; base < i1; base += 16) {
        int navail = i1 - base; if (navail > 16) navail = 16;
        int lidx = li < navail ? li : (navail - 1);
        int2 ep = cpack[base + lidx];
        for (int e = 0; e < navail; e += 4) {
            int s[4]; float w[4];
            #pragma unroll
            for (int j = 0; j < 4; ++j) {
                int idx = e + j;
                int cl = idx < navail ? idx : (navail - 1);
                s[j] = __shfl(ep.x, cl, 16);
                float wj = __int_as_float(__shfl(ep.y, cl, 16));
                w[j] = idx < navail ? wj : 0.f;
            }
            uint4 h[4];
            #pragma unroll
            for (int j = 0; j < 4; ++j) h[j] = H4[(size_t)s[j] * 16 + li];
            #pragma unroll
            for (int j = 0; j < 4; ++j) {
                float2 f;
                f = __half22float2(*(const __half2*)&h[j].x); acc[0] += f.x * w[j]; acc[1] += f.y * w[j];
                f = __half22float2(*(const __half2*)&h[j].y); acc[2] += f.x * w[j]; acc[3] += f.y * w[j];
                f = __half22float2(*(const __half2*)&h[j].z); acc[4] += f.x * w[j]; acc[5] += f.y * w[j];
                f = __half22float2(*(const __half2*)&h[j].w); acc[6] += f.x * w[j]; acc[7] += f.y * w[j];
            }
        }
    }

    float4 b0 = *(const float4*)&bias[li * 8];
    float4 b1 = *(const float4*)&bias[li * 8 + 4];
    acc[0] += b0.x; acc[1] += b0.y; acc[2] += b0.z; acc[3] += b0.w;
    acc[4] += b1.x; acc[5] += b1.y; acc[6] += b1.z; acc[7] += b1.w;
    if (do_relu) {
        #pragma unroll
        for (int k = 0; k < 8; ++k) acc[k] = fmaxf(acc[k], 0.f);
    }
    if (OUT_HALF) {
        __half2 p0 = __float22half2_rn(make_float2(acc[0], acc[1]));
        __half2 p1 = __float22half2_rn(make_float2(acc[2], acc[3]));
        __half2 p2 = __float22half2_rn(make_float2(acc[4], acc[5]));
        __half2 p3 = __float22half2_rn(make_float2(acc[6], acc[7]));
        uint4 pk;
        pk.x = *(unsigned int*)&p0; pk.y = *(unsigned int*)&p1;
        pk.z = *(unsigned int*)&p2; pk.w = *(unsigned int*)&p3;
        ((uint4*)Yv)[(size_t)node * 16 + li] = pk;
    } else {
        float* Yf = (float*)Yv;
        *(float4*)&Yf[(size_t)node * 128 + li * 8]     = make_float4(acc[0], acc[1], acc[2], acc[3]);
        *(float4*)&Yf[(size_t)node * 128 + li * 8 + 4] = make_float4(acc[4], acc[5], acc[6], acc[7]);
    }
}

// ---------------- launch ----------------

extern "C" void kernel_launch(void* const* d_in, const int* in_sizes, int n_in,
                              void* d_out, int out_size, void* d_ws, size_t ws_size,
                              hipStream_t stream) {
    const int*   label = (const int*)d_in[0];
    const float* bbox  = (const float*)d_in[1];
    const int*   eidx  = (const int*)d_in[2];
    const float* emb   = (const float*)d_in[3];
    const float* w1    = (const float*)d_in[4];
    const float* b1    = (const float*)d_in[5];
    const float* w2    = (const float*)d_in[6];
    const float* b2    = (const float*)d_in[7];
    const float* wg0   = (const float*)d_in[8];
    const float* bg0   = (const float*)d_in[9];
    const float* wg1   = (const float*)d_in[10];
    const float* bg1   = (const float*)d_in[11];
    const float* wg2   = (const float*)d_in[12];
    const float* bg2   = (const float*)d_in[13];

    int N = in_sizes[0];
    int E = in_sizes[2] / 2;
    const int* esrc = eidx;
    const int* edst = eidx + E;

    char* ws = (char*)d_ws;
    int*       offs     = (int*)      (ws + 0x80000);    // N+1 ints
    int*       partials = (int*)      (ws + 0x100000);   // <=512 ints
    float*     dinv     = (float*)    (ws + 0x180000);   // N floats
    _Float16*  WT       = (_Float16*) (ws + 0x1C0000);   // 3*128*128 halves (96 KB)
    long long* cpack    = (long long*)(ws + 0x200000);   // (E+N) int2 (~13.6 MB)
    __half*    F0       = (__half*)   (ws + 0x1000000);  // N*128 halves (25.6 MB)
    int*       cnt_pad  = (int*)      (ws + 0x1000000);  // N*16 ints (6.4 MB) — aliases F0 (dead before k_feat)
    int*       rank     = (int*)      (ws + 0x1800000);  // E ints (6.4 MB) — aliases F0 tail (dead before k_feat)
    __half*    G        = (__half*)   (ws + 0x2900000);  // N*128 halves (25.6 MB)
    __half*    F1       = (__half*)   d_out;             // fp16 scratch (layer-1 window only)
    float*     Of       = (float*)    d_out;             // final fp32 output

    int nb = (N + 255) / 256;
    int eb = (E + 255) / 256;

    hipMemsetAsync(cnt_pad, 0, (size_t)N * CNT_PAD * 4, stream);
    k_count_rank<<<eb, 256, 0, stream>>>(edst, cnt_pad, rank, E);
    k_scan_a<<<nb, 256, 0, stream>>>(cnt_pad, offs, partials, dinv, N);
    k_scan_b<<<1, 512, 0, stream>>>(partials, nb);
    k_scan_c<<<(N + 1 + 255) / 256, 256, 0, stream>>>(offs, partials, N, nb);
    k_fill2<<<eb, 256, 0, stream>>>(esrc, edst, rank, offs, dinv, cpack, E);
    k_fill_loops<<<nb, 256, 0, stream>>>(offs, dinv, cpack, N);

    k_prep_w<<<192, 256, 0, stream>>>(wg0, wg1, wg2, WT);
    k_feat<<<(N + 3) / 4, 256, 0, stream>>>(label, bbox, emb, w1, b1, w2, b2, F0, N);

    int gemm_grid = (N + 63) / 64;
    int agg_grid  = (N + 15) / 16;

    // layer 0: G = F0 @ W0 ; F1 = relu(A_hat G + b0)
    k_gemm_mfma<<<gemm_grid, 256, 0, stream>>>((const _Float16*)F0, WT + 0 * 16384, (_Float16*)G, N);
    k_agg<1><<<agg_grid, 256, 0, stream>>>((const uint4*)G, offs, (const int2*)cpack, bg0, F1, N, 1);
    // layer 1: G = F1 @ W1 ; F0 = relu(A_hat G + b1)
    k_gemm_mfma<<<gemm_grid, 256, 0, stream>>>((const _Float16*)F1, WT + 1 * 16384, (_Float16*)G, N);
    k_agg<1><<<agg_grid, 256, 0, stream>>>((const uint4*)G, offs, (const int2*)cpack, bg1, F0, N, 1);
    // layer 2: G = F0 @ W2 ; d_out = A_hat G + b2   (fp32)
    k_gemm_mfma<<<gemm_grid, 256, 0, stream>>>((const _Float16*)F0, WT + 2 * 16384, (_Float16*)G, N);
    k_agg<0><<<agg_grid, 256, 0, stream>>>((const uint4*)G, offs, (const int2*)cpack, bg2, Of, N, 0);
}

// Round 10
// 438.894 us; speedup vs baseline: 1.1565x; 1.0867x over previous
//
#include <hip/hip_runtime.h>
#include <hip/hip_bf16.h>
#include <hip/hip_fp16.h>
#include <cstdint>
#include <cstddef>

typedef _Float16 h8 __attribute__((ext_vector_type(8)));
typedef float f4 __attribute__((ext_vector_type(4)));

#define CNT_PAD 16   // one counter per 64B line

// ---------------- CSR build ----------------

__global__ __launch_bounds__(256) void k_count_rank(const int* __restrict__ dst, int* __restrict__ cnt_pad,
                                                    int* __restrict__ rank, int E) {
    int i = blockIdx.x * 256 + threadIdx.x;
    if (i < E) rank[i] = atomicAdd(&cnt_pad[(size_t)dst[i] * CNT_PAD], 1);
}

__global__ __launch_bounds__(256) void k_scan_a(const int* __restrict__ cnt_pad, int* __restrict__ offs,
                                                int* __restrict__ partials, float* __restrict__ dinv, int N) {
    __shared__ int sh[256];
    int t = threadIdx.x;
    int i = blockIdx.x * 256 + t;
    int v = (i < N) ? (cnt_pad[(size_t)i * CNT_PAD] + 1) : 0;
    sh[t] = v;
    __syncthreads();
    for (int d = 1; d < 256; d <<= 1) {
        int add = (t >= d) ? sh[t - d] : 0;
        __syncthreads();
        sh[t] += add;
        __syncthreads();
    }
    if (i < N) {
        offs[i] = sh[t] - v;
        dinv[i] = rsqrtf((float)v);
    }
    if (t == 255) partials[blockIdx.x] = sh[255];
}

__global__ __launch_bounds__(512) void k_scan_b(int* __restrict__ partials, int nb) {
    __shared__ int sh[512];
    int t = threadIdx.x;
    int v = (t < nb) ? partials[t] : 0;
    sh[t] = v;
    __syncthreads();
    for (int d = 1; d < 512; d <<= 1) {
        int add = (t >= d) ? sh[t - d] : 0;
        __syncthreads();
        sh[t] += add;
        __syncthreads();
    }
    if (t < nb) partials[t] = sh[t];
}

__global__ __launch_bounds__(256) void k_scan_c(int* __restrict__ offs, const int* __restrict__ partials,
                                                int N, int nb) {
    int i = blockIdx.x * 256 + threadIdx.x;
    if (i < N) {
        int b = i >> 8;
        if (b > 0) offs[i] += partials[b - 1];
    } else if (i == N) {
        offs[N] = partials[nb - 1];
    }
}

__global__ __launch_bounds__(256) void k_fill2(const int* __restrict__ src, const int* __restrict__ dst,
                                               const int* __restrict__ rank, const int* __restrict__ offs,
                                               const float* __restrict__ dinv,
                                               long long* __restrict__ cpack, int E) {
    int i = blockIdx.x * 256 + threadIdx.x;
    if (i < E) {
        int s = src[i], d = dst[i];
        int pos = offs[d] + rank[i];
        unsigned int nrm = (unsigned int)__float_as_int(dinv[s] * dinv[d]);
        long long v = ((long long)nrm << 32) | (unsigned int)s;
        __builtin_nontemporal_store(v, &cpack[pos]);
    }
}

__global__ __launch_bounds__(256) void k_fill_loops(const int* __restrict__ offs,
                                                    const float* __restrict__ dinv,
                                                    long long* __restrict__ cpack, int N) {
    int i = blockIdx.x * 256 + threadIdx.x;
    if (i < N) {
        float di = dinv[i];
        unsigned int nrm = (unsigned int)__float_as_int(di * di);
        long long v = ((long long)nrm << 32) | (unsigned int)i;
        __builtin_nontemporal_store(v, &cpack[offs[i + 1] - 1]);
    }
}

// ---------------- W -> W^T fp16 (once): WT[layer][c][k] = W_layer[k][c] ----------------

__global__ __launch_bounds__(256) void k_prep_w(const float* __restrict__ w0, const float* __restrict__ w1,
                                                const float* __restrict__ w2, _Float16* __restrict__ WT) {
    int idx = blockIdx.x * 256 + threadIdx.x;
    if (idx >= 3 * 16384) return;
    int l = idx >> 14, rem = idx & 16383, c = rem >> 7, k = rem & 127;
    const float* W = (l == 0) ? w0 : (l == 1) ? w1 : w2;
    WT[idx] = (_Float16)W[k * 128 + c];
}

// ---------------- node features: x = [emb[label], MLP(bbox)] -> fp16 ----------------
// 32 nodes/block. Phase 1: h1 = relu(bbox@w1+b1) -> LDS fp16 [32][72] (pad->2-way);
// also emb gather/store. Phase 2: MFMA [32][64] @ w2 via w2^T fp16 LDS; +b2; store.

__global__ __launch_bounds__(256) void k_feat(const int* __restrict__ label, const float* __restrict__ bbox,
                                              const float* __restrict__ emb,
                                              const float* __restrict__ w1, const float* __restrict__ b1,
                                              const float* __restrict__ w2, const float* __restrict__ b2,
                                              __half* __restrict__ X, int N) {
    __shared__ float w1s[4 * 64];
    __shared__ float b1s[64], b2s[64];
    __shared__ _Float16 w2t[64][72];   // w2t[c][k] = w2[k][c]
    __shared__ _Float16 h1s[32][72];

    int t = threadIdx.x;
    if (t < 256) w1s[t] = w1[t];
    if (t < 64) { b1s[t] = b1[t]; b2s[t] = b2[t]; }
    #pragma unroll
    for (int i = 0; i < 16; ++i) {
        int idx = t + i * 256;                 // 0..4095
        int k = idx >> 6, c = idx & 63;
        w2t[c][k] = (_Float16)w2[idx];         // coalesced read, transposed LDS write
    }

    int wv = t >> 6, lane = t & 63;
    int r = lane & 15, q = lane >> 4;
    int blockBase = blockIdx.x * 32;
    int nb0 = __builtin_amdgcn_readfirstlane(blockBase + wv * 8);

    // phase 1
    #pragma unroll
    for (int nn = 0; nn < 8; ++nn) {
        int node = nb0 + nn;
        float h1 = 0.f;
        if (node < N) {
            float bb0 = bbox[node * 4 + 0];
            float bb1 = bbox[node * 4 + 1];
            float bb2 = bbox[node * 4 + 2];
            float bb3 = bbox[node * 4 + 3];
            h1 = bb0 * w1s[lane] + bb1 * w1s[64 + lane]
               + bb2 * w1s[128 + lane] + bb3 * w1s[192 + lane] + b1s[lane];
            h1 = fmaxf(h1, 0.f);
            int lb = label[node];
            X[(size_t)node * 128 + lane] = __float2half(emb[(size_t)lb * 64 + lane]);
        }
        h1s[wv * 8 + nn][lane] = (_Float16)h1;
    }
    __syncthreads();

    // phase 2: wave = (row-tile rt, col-half ch); 2 col-tiles x (K=64 -> 2 mfma) each
    int rt = wv & 1;
    int ch = wv >> 1;
    h8 a0 = *(const h8*)&h1s[rt * 16 + r][q * 8];
    h8 a1 = *(const h8*)&h1s[rt * 16 + r][32 + q * 8];
    #pragma unroll
    for (int ct = 0; ct < 2; ++ct) {
        int col = ch * 32 + ct * 16 + r;
        h8 bv0 = *(const h8*)&w2t[col][q * 8];
        h8 bv1 = *(const h8*)&w2t[col][32 + q * 8];
        f4 acc = {0.f, 0.f, 0.f, 0.f};
        acc = __builtin_amdgcn_mfma_f32_16x16x32_f16(a0, bv0, acc, 0, 0, 0);
        acc = __builtin_amdgcn_mfma_f32_16x16x32_f16(a1, bv1, acc, 0, 0, 0);
        float bb = b2s[col];
        #pragma unroll
        for (int i = 0; i < 4; ++i) {
            int node = blockBase + rt * 16 + q * 4 + i;
            if (node < N) X[(size_t)node * 128 + 64 + col] = __float2half(acc[i] + bb);
        }
    }
}

// ---------------- MFMA GEMM: H[N][128] = X[N][128] @ W  (fp16 in/out, fp32 acc) ----------------

__global__ __launch_bounds__(256) void k_gemm_mfma(const _Float16* __restrict__ X,
                                                   const _Float16* __restrict__ WT,
                                                   _Float16* __restrict__ H, int N) {
    int t = threadIdx.x;
    int wv = t >> 6, lane = t & 63;
    int r = lane & 15, q = lane >> 4;
    int n0 = blockIdx.x * 64 + wv * 16;

    int arow = n0 + r; if (arow > N - 1) arow = N - 1;
    h8 a[4];
    #pragma unroll
    for (int s = 0; s < 4; ++s)
        a[s] = *(const h8*)&X[(size_t)arow * 128 + s * 32 + q * 8];

    #pragma unroll
    for (int ct = 0; ct < 8; ++ct) {
        h8 b[4];
        #pragma unroll
        for (int s = 0; s < 4; ++s)
            b[s] = *(const h8*)&WT[(size_t)(ct * 16 + r) * 128 + s * 32 + q * 8];
        f4 acc = {0.f, 0.f, 0.f, 0.f};
        #pragma unroll
        for (int s = 0; s < 4; ++s)
            acc = __builtin_amdgcn_mfma_f32_16x16x32_f16(a[s], b[s], acc, 0, 0, 0);
        #pragma unroll
        for (int i = 0; i < 4; ++i) {
            int row = n0 + q * 4 + i;
            if (row < N) H[(size_t)row * 128 + ct * 16 + r] = (_Float16)acc[i];
        }
    }
}

// ---------------- aggregation: Y[n] = relu?( sum_e norm_e * H[src_e] + b ) ----------------
// One independent 16-lane group per node; 2-deep quad pipeline: issue quad e+4's
// 4 dwordx4 gathers before FMA-ing quad e -> 8 rows in flight steady-state.

#define FMA8(hv, wv_)                                                                        \
    {                                                                                        \
        float2 f;                                                                            \
        f = __half22float2(*(const __half2*)&(hv).x); acc[0] += f.x * (wv_); acc[1] += f.y * (wv_); \
        f = __half22float2(*(const __half2*)&(hv).y); acc[2] += f.x * (wv_); acc[3] += f.y * (wv_); \
        f = __half22float2(*(const __half2*)&(hv).z); acc[4] += f.x * (wv_); acc[5] += f.y * (wv_); \
        f = __half22float2(*(const __half2*)&(hv).w); acc[6] += f.x * (wv_); acc[7] += f.y * (wv_); \
    }

template <int OUT_HALF>
__global__ __launch_bounds__(256) void k_agg(const uint4* __restrict__ H4, const int* __restrict__ offs,
                                             const int2* __restrict__ cpack,
                                             const float* __restrict__ bias, void* __restrict__ Yv,
                                             int N, int do_relu) {
    int node = blockIdx.x * 16 + (threadIdx.x >> 4);
    if (node >= N) return;
    int li = threadIdx.x & 15;
    int i0 = offs[node], i1 = offs[node + 1];

    float acc[8];
    #pragma unroll
    for (int k = 0; k < 8; ++k) acc[k] = 0.f;

    for (int base = i0; base < i1; base += 16) {
        int navail = i1 - base; if (navail > 16) navail = 16;
        int lidx = li < navail ? li : (navail - 1);
        int2 ep = cpack[base + lidx];

        float wA[4]; uint4 hA[4];
        #pragma unroll
        for (int j = 0; j < 4; ++j) {
            int cl = j < navail ? j : (navail - 1);
            int s = __shfl(ep.x, cl, 16);
            float wj = __int_as_float(__shfl(ep.y, cl, 16));
            wA[j] = j < navail ? wj : 0.f;
            hA[j] = H4[(size_t)s * 16 + li];
        }
        for (int e = 4; e < navail; e += 4) {
            float wB[4]; uint4 hB[4];
            #pragma unroll
            for (int j = 0; j < 4; ++j) {
                int idx = e + j;
                int cl = idx < navail ? idx : (navail - 1);
                int s = __shfl(ep.x, cl, 16);
                float wj = __int_as_float(__shfl(ep.y, cl, 16));
                wB[j] = idx < navail ? wj : 0.f;
                hB[j] = H4[(size_t)s * 16 + li];
            }
            #pragma unroll
            for (int j = 0; j < 4; ++j) FMA8(hA[j], wA[j]);
            #pragma unroll
            for (int j = 0; j < 4; ++j) { wA[j] = wB[j]; hA[j] = hB[j]; }
        }
        #pragma unroll
        for (int j = 0; j < 4; ++j) FMA8(hA[j], wA[j]);
    }

    float4 b0 = *(const float4*)&bias[li * 8];
    float4 b1 = *(const float4*)&bias[li * 8 + 4];
    acc[0] += b0.x; acc[1] += b0.y; acc[2] += b0.z; acc[3] += b0.w;
    acc[4] += b1.x; acc[5] += b1.y; acc[6] += b1.z; acc[7] += b1.w;
    if (do_relu) {
        #pragma unroll
        for (int k = 0; k < 8; ++k) acc[k] = fmaxf(acc[k], 0.f);
    }
    if (OUT_HALF) {
        __half2 p0 = __float22half2_rn(make_float2(acc[0], acc[1]));
        __half2 p1 = __float22half2_rn(make_float2(acc[2], acc[3]));
        __half2 p2 = __float22half2_rn(make_float2(acc[4], acc[5]));
        __half2 p3 = __float22half2_rn(make_float2(acc[6], acc[7]));
        uint4 pk;
        pk.x = *(unsigned int*)&p0; pk.y = *(unsigned int*)&p1;
        pk.z = *(unsigned int*)&p2; pk.w = *(unsigned int*)&p3;
        ((uint4*)Yv)[(size_t)node * 16 + li] = pk;
    } else {
        float* Yf = (float*)Yv;
        *(float4*)&Yf[(size_t)node * 128 + li * 8]     = make_float4(acc[0], acc[1], acc[2], acc[3]);
        *(float4*)&Yf[(size_t)node * 128 + li * 8 + 4] = make_float4(acc[4], acc[5], acc[6], acc[7]);
    }
}

// ---------------- launch ----------------

extern "C" void kernel_launch(void* const* d_in, const int* in_sizes, int n_in,
                              void* d_out, int out_size, void* d_ws, size_t ws_size,
                              hipStream_t stream) {
    const int*   label = (const int*)d_in[0];
    const float* bbox  = (const float*)d_in[1];
    const int*   eidx  = (const int*)d_in[2];
    const float* emb   = (const float*)d_in[3];
    const float* w1    = (const float*)d_in[4];
    const float* b1    = (const float*)d_in[5];
    const float* w2    = (const float*)d_in[6];
    const float* b2    = (const float*)d_in[7];
    const float* wg0   = (const float*)d_in[8];
    const float* bg0   = (const float*)d_in[9];
    const float* wg1   = (const float*)d_in[10];
    const float* bg1   = (const float*)d_in[11];
    const float* wg2   = (const float*)d_in[12];
    const float* bg2   = (const float*)d_in[13];

    int N = in_sizes[0];
    int E = in_sizes[2] / 2;
    const int* esrc = eidx;
    const int* edst = eidx + E;

    char* ws = (char*)d_ws;
    int*       offs     = (int*)      (ws + 0x80000);    // N+1 ints
    int*       partials = (int*)      (ws + 0x100000);   // <=512 ints
    float*     dinv     = (float*)    (ws + 0x180000);   // N floats
    _Float16*  WT       = (_Float16*) (ws + 0x1C0000);   // 3*128*128 halves (96 KB)
    long long* cpack    = (long long*)(ws + 0x200000);   // (E+N) int2 (~13.6 MB)
    __half*    F0       = (__half*)   (ws + 0x1000000);  // N*128 halves (25.6 MB)
    int*       cnt_pad  = (int*)      (ws + 0x1000000);  // N*16 ints (6.4 MB) — aliases F0 (dead before k_feat)
    int*       rank     = (int*)      (ws + 0x1800000);  // E ints (6.4 MB) — aliases F0 tail (dead before k_feat)
    __half*    G        = (__half*)   (ws + 0x2900000);  // N*128 halves (25.6 MB)
    __half*    F1       = (__half*)   d_out;             // fp16 scratch (layer-1 window only)
    float*     Of       = (float*)    d_out;             // final fp32 output

    int nb = (N + 255) / 256;
    int eb = (E + 255) / 256;

    hipMemsetAsync(cnt_pad, 0, (size_t)N * CNT_PAD * 4, stream);
    k_count_rank<<<eb, 256, 0, stream>>>(edst, cnt_pad, rank, E);
    k_scan_a<<<nb, 256, 0, stream>>>(cnt_pad, offs, partials, dinv, N);
    k_scan_b<<<1, 512, 0, stream>>>(partials, nb);
    k_scan_c<<<(N + 1 + 255) / 256, 256, 0, stream>>>(offs, partials, N, nb);
    k_fill2<<<eb, 256, 0, stream>>>(esrc, edst, rank, offs, dinv, cpack, E);
    k_fill_loops<<<nb, 256, 0, stream>>>(offs, dinv, cpack, N);

    k_prep_w<<<192, 256, 0, stream>>>(wg0, wg1, wg2, WT);
    k_feat<<<(N + 31) / 32, 256, 0, stream>>>(label, bbox, emb, w1, b1, w2, b2, F0, N);

    int gemm_grid = (N + 63) / 64;
    int agg_grid  = (N + 15) / 16;

    // layer 0: G = F0 @ W0 ; F1 = relu(A_hat G + b0)
    k_gemm_mfma<<<gemm_grid, 256, 0, stream>>>((const _Float16*)F0, WT + 0 * 16384, (_Float16*)G, N);
    k_agg<1><<<agg_grid, 256, 0, stream>>>((const uint4*)G, offs, (const int2*)cpack, bg0, F1, N, 1);
    // layer 1: G = F1 @ W1 ; F0 = relu(A_hat G + b1)
    k_gemm_mfma<<<gemm_grid, 256, 0, stream>>>((const _Float16*)F1, WT + 1 * 16384, (_Float16*)G, N);
    k_agg<1><<<agg_grid, 256, 0, stream>>>((const uint4*)G, offs, (const int2*)cpack, bg1, F0, N, 1);
    // layer 2: G = F0 @ W2 ; d_out = A_hat G + b2   (fp32)
    k_gemm_mfma<<<gemm_grid, 256, 0, stream>>>((const _Float16*)F0, WT + 2 * 16384, (_Float16*)G, N);
    k_agg<0><<<agg_grid, 256, 0, stream>>>((const uint4*)G, offs, (const int2*)cpack, bg2, Of, N, 0);
}